// Round 7
// baseline (109.940 us; speedup 1.0000x reference)
//
#include <hip/hip_runtime.h>
#include <math.h>
#include <float.h>

// VQ-VAE quantizer, round 7: round-6 structure (A direct from L2, no mid-loop
// barriers) + register discipline:
//  - x hi/lo fp16 fragments PINNED in registers via asm "+v" (round 6's
//    VGPR_Count=56 proved the compiler sank them into the loop -> reload/chunk)
//  - A-fragments in an 8-slot rolling register window: chunk c+1's loads
//    overwrite slots as chunk c consumes them (~8 loads in flight)
//  - split accumulators (ds 0-3 / 4-7) halve the serial MFMA chain
// score(t,k) = x.eh_k - |e_k|^2/2, x = xh+xl exact fp16 pair (2 MFMAs/K-step).
// Packed top-2 per quarter (score | 1023-k), exact fp32 rescore of 8
// candidates -> argmin (verified hedge rounds 1-6).

typedef __attribute__((ext_vector_type(8))) _Float16 f16x8;
typedef __attribute__((ext_vector_type(16))) float f32x16;

#define QT_OFF    0        // 32 pts * 512 B quantized tile (epilogue)
#define EH2_OFF   16384    // 4 KB: -0.5*|e|^2 all 1024 codes
#define KCND_OFF  20480    // 8*32 ints
#define SCS_OFF   21504    // 8*32 floats
#define KFIN_OFF  22528    // 32 ints
#define WSUM_OFF  22656    // 4 floats
#define SMEM_BYTES 22672

typedef __attribute__((address_space(1))) const void gas_t;
typedef __attribute__((address_space(3))) void las_t;
__device__ __forceinline__ void glds16(const void* g, void* l) {
  __builtin_amdgcn_global_load_lds((gas_t*)g, (las_t*)l, 16, 0, 0);
}

#define PIN8(a) asm volatile("" : "+v"(a[0]), "+v"(a[1]), "+v"(a[2]), \
    "+v"(a[3]), "+v"(a[4]), "+v"(a[5]), "+v"(a[6]), "+v"(a[7]))

// ---- prep: emb f32 -> eh fp16 [1024][128] + eh2 = -0.5*|e|^2 (f32) ----
__global__ __launch_bounds__(256)
void vq_prep(const float* __restrict__ emb, _Float16* __restrict__ ehg,
             float* __restrict__ eh2g) {
  const int tid = threadIdx.x;
  const int r = blockIdx.x * 16 + (tid >> 4);
  const int seg = tid & 15;
  const float* row = emb + (size_t)r * 128 + seg * 8;
  float4 f0 = *(const float4*)&row[0];
  float4 f1 = *(const float4*)&row[4];
  float fv[8] = {f0.x, f0.y, f0.z, f0.w, f1.x, f1.y, f1.z, f1.w};
  f16x8 H;
  float ssq = 0.f;
#pragma unroll
  for (int j = 0; j < 8; ++j) {
    float f = fv[j];
    ssq = fmaf(f, f, ssq);
    H[j] = (_Float16)f;
  }
  *(f16x8*)(ehg + (size_t)r * 128 + seg * 8) = H;
#pragma unroll
  for (int off = 1; off < 16; off <<= 1) ssq += __shfl_xor(ssq, off, 64);
  if (seg == 0) eh2g[r] = -0.5f * ssq;
}

__global__ __launch_bounds__(256, 4)
void vq_main(const float* __restrict__ x, const float* __restrict__ emb,
             const _Float16* __restrict__ ehg, const float* __restrict__ eh2g,
             float* __restrict__ out, float* __restrict__ partial) {
  __shared__ __align__(16) char smem[SMEM_BYTES];
  float* eh2s = (float*)(smem + EH2_OFF);
  int*   kcnd = (int*)(smem + KCND_OFF);
  float* scs  = (float*)(smem + SCS_OFF);
  int*   kfin = (int*)(smem + KFIN_OFF);
  float* wsum = (float*)(smem + WSUM_OFF);

  const int tid = threadIdx.x;
  const int lane = tid & 63;
  const int w = tid >> 6;          // codebook quarter (256 codes)
  const int hf = lane >> 5;        // K-half of mfma fragment
  const int c32 = lane & 31;       // mfma column = point; also A code row
  const int blk = blockIdx.x;
  const int b = blk >> 6;
  const int t0 = (blk & 63) << 5;  // 32-point tile
  const size_t bOff = (size_t)b * 262144;

  // stage eh2 (4 KB) async; drained by the pre-loop barrier
  glds16((const char*)eh2g + tid * 16, smem + EH2_OFF + tid * 16);

  // ---- x B-fragments: fp32 global (coalesced 128B segments) -> fp16 pairs ----
  f16x8 xh[8], xl[8];
  {
    const float* xp = x + bOff + t0 + c32;
    const int dbase = hf * 8;
#pragma unroll
    for (int ds = 0; ds < 8; ++ds)
#pragma unroll
      for (int j = 0; j < 8; ++j) {
        float f = xp[(size_t)(ds * 16 + dbase + j) * 2048];
        _Float16 h = (_Float16)f;
        xh[ds][j] = h;
        xl[ds][j] = (_Float16)(f - (float)h);
      }
  }

  // ---- A rolling window: preload chunk 0 ----
  const _Float16* abase = ehg + ((size_t)(w * 256 + c32) * 128) + hf * 8;
  f16x8 A[8];
#pragma unroll
  for (int ds = 0; ds < 8; ++ds) A[ds] = *(const f16x8*)(abase + ds * 16);

  __syncthreads();   // eh2 staged

  const float NEG = __uint_as_float(0xFF800000u);   // -inf
  float v1 = NEG, v2 = NEG;

#pragma unroll
  for (int c = 0; c < 8; ++c) {
    PIN8(xh); PIN8(xl);            // forbid remat/sinking of x fragments
    const int kb = w * 256 + c * 32;
    // accA init: -0.5*|e_k|^2 (broadcast LDS reads); accB init: 0
    f32x16 accA, accB;
#pragma unroll
    for (int q = 0; q < 4; ++q) {
      float4 v = *(const float4*)&eh2s[kb + 4 * hf + 8 * q];
      accA[4*q+0] = v.x; accA[4*q+1] = v.y;
      accA[4*q+2] = v.z; accA[4*q+3] = v.w;
      accB[4*q+0] = 0.f; accB[4*q+1] = 0.f;
      accB[4*q+2] = 0.f; accB[4*q+3] = 0.f;
    }
    const _Float16* nbase = abase + (size_t)(c + 1) * 4096;
#pragma unroll
    for (int ds = 0; ds < 8; ++ds) {
      f16x8 av = A[ds];
      if (c < 7) A[ds] = *(const f16x8*)(nbase + ds * 16);  // prefetch c+1
      if (ds < 4) {
        accA = __builtin_amdgcn_mfma_f32_32x32x16_f16(av, xh[ds], accA, 0, 0, 0);
        accA = __builtin_amdgcn_mfma_f32_32x32x16_f16(av, xl[ds], accA, 0, 0, 0);
      } else {
        accB = __builtin_amdgcn_mfma_f32_32x32x16_f16(av, xh[ds], accB, 0, 0, 0);
        accB = __builtin_amdgcn_mfma_f32_32x32x16_f16(av, xl[ds], accB, 0, 0, 0);
      }
    }
    // packed top-2: low 10 mantissa bits <- (1023 - k)
    const int tb = 1023 - kb - 4 * hf;
#pragma unroll
    for (int r = 0; r < 16; ++r) {
      float s = accA[r] + accB[r];
      unsigned pc = (unsigned)(tb - ((r & 3) + 8 * (r >> 2)));
      float p = __uint_as_float((__float_as_uint(s) & 0xFFFFFC00u) | pc);
      float ov1 = v1;
      v1 = fmaxf(v1, p);
      v2 = fmaxf(fminf(p, ov1), v2);
    }
  }

  // merge hf halves -> per-point top-2 of this quarter
  {
    float m1 = __shfl_xor(v1, 32, 64);
    float m2 = __shfl_xor(v2, 32, 64);
    float c1 = fmaxf(v1, m1);
    float c2 = fmaxf(fminf(v1, m1), fmaxf(v2, m2));
    if (hf == 0) {
      kcnd[(w * 2 + 0) * 32 + c32] = 1023 - (int)(__float_as_uint(c1) & 1023u);
      kcnd[(w * 2 + 1) * 32 + c32] = 1023 - (int)(__float_as_uint(c2) & 1023u);
    }
  }
  __syncthreads();

  // exact fp32 rescore of 8 candidates: sc = x.e - |e|^2/2 (maximize)
  {
    const int p = tid & 31, cand = tid >> 5;
    const int kc = kcnd[cand * 32 + p];
    const float* xc = x + bOff + t0 + p;
    const float* er = emb + (size_t)kc * 128;
    float dsum = 0.f;
#pragma unroll 4
    for (int d4 = 0; d4 < 128; d4 += 4) {
      float4 e4 = *(const float4*)&er[d4];
      dsum = fmaf(xc[(size_t)(d4 + 0) * 2048], e4.x, dsum);
      dsum = fmaf(xc[(size_t)(d4 + 1) * 2048], e4.y, dsum);
      dsum = fmaf(xc[(size_t)(d4 + 2) * 2048], e4.z, dsum);
      dsum = fmaf(xc[(size_t)(d4 + 3) * 2048], e4.w, dsum);
    }
    scs[cand * 32 + p] = dsum + eh2s[kc];
  }
  __syncthreads();
  if (tid < 32) {
    float bs = scs[tid]; int bk = kcnd[tid];
#pragma unroll
    for (int cd = 1; cd < 8; ++cd) {
      float v = scs[cd * 32 + tid];
      int k = kcnd[cd * 32 + tid];
      if (v > bs || (v == bs && k < bk)) { bs = v; bk = k; }
    }
    kfin[tid] = bk;
  }
  __syncthreads();

  // E1: gather emb rows -> qt (slot-XOR swizzled)
  {
    const int p = tid >> 3, seg = tid & 7;
    const float* er = emb + (size_t)kfin[p] * 128 + seg * 16;
#pragma unroll
    for (int j = 0; j < 4; ++j) {
      int slot = seg * 4 + j;
      int sw = slot ^ (p & 31);
      *(float4*)(smem + QT_OFF + p * 512 + sw * 16) = *(const float4*)&er[j * 4];
    }
  }
  __syncthreads();

  // E2: lane = point; read qt along d, coalesced stores along t
  float lsum = 0.f;
  {
    const int p = tid & 31, jb = tid >> 5;
    const float* xg = x + bOff + t0 + p;
    float* og = out + bOff + t0 + p;
#pragma unroll
    for (int i = 0; i < 4; ++i) {
      int slot = jb * 4 + i;
      int sw = slot ^ (p & 31);
      float4 q4 = *(const float4*)(smem + QT_OFF + p * 512 + sw * 16);
      float qa[4] = {q4.x, q4.y, q4.z, q4.w};
      int dd = slot * 4;
#pragma unroll
      for (int i2 = 0; i2 < 4; ++i2) {
        float xv = xg[(size_t)(dd + i2) * 2048];
        float df = qa[i2] - xv;
        lsum = fmaf(df, df, lsum);
        og[(size_t)(dd + i2) * 2048] = qa[i2];
      }
    }
  }
#pragma unroll
  for (int off = 32; off; off >>= 1) lsum += __shfl_down(lsum, off, 64);
  if (lane == 0) wsum[w] = lsum;
  __syncthreads();
  if (tid == 0) partial[blk] = (wsum[0] + wsum[1]) + (wsum[2] + wsum[3]);
}

__global__ void vq_loss(const float* __restrict__ partial, float* __restrict__ out) {
  int lane = threadIdx.x;  // 64 threads, 1024 partials
  float s = 0.f;
#pragma unroll
  for (int i = 0; i < 16; ++i) s += partial[i * 64 + lane];
#pragma unroll
  for (int off = 32; off; off >>= 1) s += __shfl_down(s, off, 64);
  if (lane == 0) out[4194304] = 1.25f * s / 4194304.0f;
}

extern "C" void kernel_launch(void* const* d_in, const int* in_sizes, int n_in,
                              void* d_out, int out_size, void* d_ws, size_t ws_size,
                              hipStream_t stream) {
  const float* x   = (const float*)d_in[0];   // [16,1,128,2048]
  const float* emb = (const float*)d_in[1];   // [1024,128]
  float* out = (float*)d_out;
  char* ws = (char*)d_ws;
  _Float16* ehg = (_Float16*)ws;              // 256 KB
  float* eh2g = (float*)(ws + 262144);        // 4 KB
  float* partial = (float*)(ws + 266240);     // 4 KB (1024 floats)
  vq_prep<<<64, 256, 0, stream>>>(emb, ehg, eh2g);
  vq_main<<<1024, 256, 0, stream>>>(x, emb, ehg, eh2g, out, partial);
  vq_loss<<<1, 64, 0, stream>>>(partial, out);
}

// Round 8
// 64.843 us; speedup vs baseline: 1.6955x; 1.6955x over previous
//
#include <hip/hip_runtime.h>
#include <math.h>
#include <float.h>

// VQ-VAE quantizer, round 8: two-kernel decomposition.
// vq_main: 512 blocks x 512 thr. Block = 256 points x ONE codebook quarter
//   (64 KB fp16) staged to LDS once (XOR-swizzled), ONE barrier, then a pure
//   register loop: 8 chunks x {C-init, 8 ds_read_b128, 16 MFMA, packed top-2}.
//   Emits packed top-2 candidate codes per (point, quarter) to global.
// vq_fin: 1024 blocks x 256 thr. Exact fp32 rescore of the 8 candidates per
//   point (verified hedge, rounds 1-7), select, gather codebook row, coalesced
//   store + loss partial.
// score(t,k) = x.eh_k - |e_k|^2/2, x = xh+xl exact fp16 pair (2 MFMAs/K-step).

typedef __attribute__((ext_vector_type(8))) _Float16 f16x8;
typedef __attribute__((ext_vector_type(16))) float f32x16;

typedef __attribute__((address_space(1))) const void gas_t;
typedef __attribute__((address_space(3))) void las_t;
__device__ __forceinline__ void glds16(const void* g, void* l) {
  __builtin_amdgcn_global_load_lds((gas_t*)g, (las_t*)l, 16, 0, 0);
}

// ---- prep: emb f32 -> eh fp16 [1024][128] + eh2 = -0.5*|e|^2 (f32) ----
__global__ __launch_bounds__(256)
void vq_prep(const float* __restrict__ emb, _Float16* __restrict__ ehg,
             float* __restrict__ eh2g) {
  const int tid = threadIdx.x;
  const int r = blockIdx.x * 16 + (tid >> 4);
  const int seg = tid & 15;
  const float* row = emb + (size_t)r * 128 + seg * 8;
  float4 f0 = *(const float4*)&row[0];
  float4 f1 = *(const float4*)&row[4];
  float fv[8] = {f0.x, f0.y, f0.z, f0.w, f1.x, f1.y, f1.z, f1.w};
  f16x8 H;
  float ssq = 0.f;
#pragma unroll
  for (int j = 0; j < 8; ++j) {
    float f = fv[j];
    ssq = fmaf(f, f, ssq);
    H[j] = (_Float16)f;
  }
  *(f16x8*)(ehg + (size_t)r * 128 + seg * 8) = H;
#pragma unroll
  for (int off = 1; off < 16; off <<= 1) ssq += __shfl_xor(ssq, off, 64);
  if (seg == 0) eh2g[r] = -0.5f * ssq;
}

// ---- main: candidates only ----
#define EBUF_BYTES 65536
#define EH2S_OFF   65536
#define MAIN_SMEM  66560

__global__ __launch_bounds__(512, 4)
void vq_main(const float* __restrict__ x, const _Float16* __restrict__ ehg,
             const float* __restrict__ eh2g, int* __restrict__ kcnd_g) {
  __shared__ __align__(16) char smem[MAIN_SMEM];
  float* eh2s = (float*)(smem + EH2S_OFF);

  const int tid = threadIdx.x;
  const int lane = tid & 63;
  const int w = tid >> 6;          // wave: owns 32 points
  const int hf = lane >> 5;        // K-half of mfma fragment
  const int c32 = lane & 31;       // mfma column = point; also A code row
  const int blk = blockIdx.x;
  const int q = blk & 3;           // codebook quarter
  const int pt_base = (blk >> 2) << 8;   // 256-pt tile
  const int b = pt_base >> 11;
  const int t0 = pt_base & 2047;

  // ---- stage quarter (64 KB, inverse-swizzled src) + eh2 slice (1 KB) ----
  {
    const char* gq = (const char*)ehg + (size_t)q * EBUF_BYTES;
#pragma unroll
    for (int r = 0; r < 8; ++r) {
      int o = r * 8192 + tid * 16;
      int s = o ^ (((o >> 8) & 15) << 4);
      glds16(gq + s, smem + o);
    }
    if (tid < 64)
      glds16((const char*)eh2g + q * 1024 + tid * 16, smem + EH2S_OFF + tid * 16);
  }

  // ---- x B-fragments: fp32 global (coalesced across points) -> fp16 pairs ----
  f16x8 xh[8], xl[8];
  {
    const float* xp = x + (size_t)b * 262144 + t0 + w * 32 + c32;
    const int dbase = hf * 8;
#pragma unroll
    for (int ds = 0; ds < 8; ++ds)
#pragma unroll
      for (int j = 0; j < 8; ++j) {
        float f = xp[(size_t)(ds * 16 + dbase + j) * 2048];
        _Float16 h = (_Float16)f;
        xh[ds][j] = h;
        xl[ds][j] = (_Float16)(f - (float)h);
      }
  }
  // one-time opaque pin: forbid remat-sinking (round 6) without in-loop
  // constraints (round 7's spill)
#pragma unroll
  for (int i = 0; i < 8; ++i) {
    asm volatile("" : "+v"(xh[i]));
    asm volatile("" : "+v"(xl[i]));
  }

  __syncthreads();   // drains vmcnt: ebuf + eh2 staged

  const float NEG = __uint_as_float(0xFF800000u);   // -inf
  float v1 = NEG, v2 = NEG;

#pragma unroll
  for (int c = 0; c < 8; ++c) {
    const int kbl = c * 32;        // chunk base within quarter
    // C-init: acc[reg] = -0.5*|e_k|^2, local k = kbl + (reg&3)+8*(reg>>2)+4*hf
    f32x16 acc;
#pragma unroll
    for (int qq = 0; qq < 4; ++qq) {
      float4 v = *(const float4*)&eh2s[kbl + 4 * hf + 8 * qq];
      acc[4*qq+0] = v.x; acc[4*qq+1] = v.y;
      acc[4*qq+2] = v.z; acc[4*qq+3] = v.w;
    }
    const int rowb = (kbl + c32) * 256 + hf * 16;
    const int swz = (c32 & 15) << 4;
#pragma unroll
    for (int ds = 0; ds < 8; ++ds) {
      f16x8 ea = *(const f16x8*)(smem + ((rowb + ds * 32) ^ swz));
      acc = __builtin_amdgcn_mfma_f32_32x32x16_f16(ea, xh[ds], acc, 0, 0, 0);
      acc = __builtin_amdgcn_mfma_f32_32x32x16_f16(ea, xl[ds], acc, 0, 0, 0);
    }
    // packed top-2: low 10 mantissa bits <- (1023 - global k)
    const int tb = 1023 - (q * 256 + kbl) - 4 * hf;
#pragma unroll
    for (int r = 0; r < 16; ++r) {
      unsigned pc = (unsigned)(tb - ((r & 3) + 8 * (r >> 2)));
      float p = __uint_as_float((__float_as_uint(acc[r]) & 0xFFFFFC00u) | pc);
      float ov1 = v1;
      v1 = fmaxf(v1, p);
      v2 = fmaxf(fminf(p, ov1), v2);
    }
  }

  // merge hf halves -> per-point top-2 of this quarter; write packed to global
  {
    float m1 = __shfl_xor(v1, 32, 64);
    float m2 = __shfl_xor(v2, 32, 64);
    float c1 = fmaxf(v1, m1);
    float c2 = fmaxf(fminf(v1, m1), fmaxf(v2, m2));
    if (hf == 0) {
      int k1 = 1023 - (int)(__float_as_uint(c1) & 1023u);
      int k2 = 1023 - (int)(__float_as_uint(c2) & 1023u);
      kcnd_g[q * 32768 + pt_base + w * 32 + c32] = k1 | (k2 << 16);
    }
  }
}

// ---- fin: exact rescore of 8 candidates, gather, store, loss ----
#define QT_OFF   0        // 32 pts * 512 B
#define SCS_OFF  16384
#define KCS_OFF  17408
#define KFIN_OFF 18432
#define WSUM_OFF 18560
#define FIN_SMEM 18576

__global__ __launch_bounds__(256, 4)
void vq_fin(const float* __restrict__ x, const float* __restrict__ emb,
            const float* __restrict__ eh2g, const int* __restrict__ kcnd_g,
            float* __restrict__ out, float* __restrict__ partial) {
  __shared__ __align__(16) char smem[FIN_SMEM];
  float* scs = (float*)(smem + SCS_OFF);
  int*   kcs = (int*)(smem + KCS_OFF);
  int*   kfin = (int*)(smem + KFIN_OFF);
  float* wsum = (float*)(smem + WSUM_OFF);

  const int tid = threadIdx.x;
  const int lane = tid & 63;
  const int p = tid & 31, cand = tid >> 5;   // cand 0..7
  const int qq = cand >> 1, h = cand & 1;
  const int blk = blockIdx.x;
  const int n0 = blk << 5;                   // 32-pt tile
  const int b = n0 >> 11, t0 = n0 & 2047;
  const size_t bOff = (size_t)b * 262144;

  // exact fp32 score sc = x.e - |e|^2/2 (maximize) for this candidate
  {
    int pk = kcnd_g[qq * 32768 + n0 + p];
    int kc = (pk >> (16 * h)) & 0xFFFF;
    const float* xc = x + bOff + t0 + p;
    const float* er = emb + (size_t)kc * 128;
    float dsum = 0.f;
#pragma unroll 4
    for (int d4 = 0; d4 < 128; d4 += 4) {
      float4 e4 = *(const float4*)&er[d4];
      dsum = fmaf(xc[(size_t)(d4 + 0) * 2048], e4.x, dsum);
      dsum = fmaf(xc[(size_t)(d4 + 1) * 2048], e4.y, dsum);
      dsum = fmaf(xc[(size_t)(d4 + 2) * 2048], e4.z, dsum);
      dsum = fmaf(xc[(size_t)(d4 + 3) * 2048], e4.w, dsum);
    }
    scs[tid] = dsum + eh2g[kc];
    kcs[tid] = kc;
  }
  __syncthreads();
  if (tid < 32) {
    float bs = scs[tid]; int bk = kcs[tid];
#pragma unroll
    for (int cd = 1; cd < 8; ++cd) {
      float v = scs[cd * 32 + tid];
      int k = kcs[cd * 32 + tid];
      if (v > bs || (v == bs && k < bk)) { bs = v; bk = k; }
    }
    kfin[tid] = bk;
  }
  __syncthreads();

  // E1: gather emb rows -> qt (slot-XOR swizzled)
  {
    const int p2 = tid >> 3, seg = tid & 7;
    const float* er2 = emb + (size_t)kfin[p2] * 128 + seg * 16;
#pragma unroll
    for (int j = 0; j < 4; ++j) {
      int slot = seg * 4 + j;
      int sw = slot ^ (p2 & 31);
      *(float4*)(smem + QT_OFF + p2 * 512 + sw * 16) = *(const float4*)&er2[j * 4];
    }
  }
  __syncthreads();

  // E2: lane = point; read qt along d, coalesced stores along t + loss
  float lsum = 0.f;
  {
    const int jb = tid >> 5;
    const float* xg = x + bOff + t0 + p;
    float* og = out + bOff + t0 + p;
#pragma unroll
    for (int i = 0; i < 4; ++i) {
      int slot = jb * 4 + i;
      int sw = slot ^ (p & 31);
      float4 q4 = *(const float4*)(smem + QT_OFF + p * 512 + sw * 16);
      float qa[4] = {q4.x, q4.y, q4.z, q4.w};
      int dd = slot * 4;
#pragma unroll
      for (int i2 = 0; i2 < 4; ++i2) {
        float xv = xg[(size_t)(dd + i2) * 2048];
        float df = qa[i2] - xv;
        lsum = fmaf(df, df, lsum);
        og[(size_t)(dd + i2) * 2048] = qa[i2];
      }
    }
  }
#pragma unroll
  for (int off = 32; off; off >>= 1) lsum += __shfl_down(lsum, off, 64);
  if (lane == 0) wsum[tid >> 6] = lsum;
  __syncthreads();
  if (tid == 0) partial[blk] = (wsum[0] + wsum[1]) + (wsum[2] + wsum[3]);
}

__global__ void vq_loss(const float* __restrict__ partial, float* __restrict__ out) {
  int lane = threadIdx.x;  // 64 threads, 1024 partials
  float s = 0.f;
#pragma unroll
  for (int i = 0; i < 16; ++i) s += partial[i * 64 + lane];
#pragma unroll
  for (int off = 32; off; off >>= 1) s += __shfl_down(s, off, 64);
  if (lane == 0) out[4194304] = 1.25f * s / 4194304.0f;
}

extern "C" void kernel_launch(void* const* d_in, const int* in_sizes, int n_in,
                              void* d_out, int out_size, void* d_ws, size_t ws_size,
                              hipStream_t stream) {
  const float* x   = (const float*)d_in[0];   // [16,1,128,2048]
  const float* emb = (const float*)d_in[1];   // [1024,128]
  float* out = (float*)d_out;
  char* ws = (char*)d_ws;
  _Float16* ehg = (_Float16*)ws;              // 256 KB
  float* eh2g = (float*)(ws + 262144);        // 4 KB
  int* kcnd_g = (int*)(ws + 266240);          // 512 KB (4 quarters x 32768)
  float* partial = (float*)(ws + 790528);     // 4 KB (1024 floats)
  vq_prep<<<64, 256, 0, stream>>>(emb, ehg, eh2g);
  vq_main<<<512, 512, 0, stream>>>(x, ehg, eh2g, kcnd_g);
  vq_fin<<<1024, 256, 0, stream>>>(x, emb, eh2g, kcnd_g, out, partial);
  vq_loss<<<1, 64, 0, stream>>>(partial, out);
}